// Round 1
// 1786.590 us; speedup vs baseline: 1.1223x; 1.1223x over previous
//
#include <hip/hip_runtime.h>

// LSTM: B=32, S=2048, I=H=256. All global tensors float32.
// d_in: 0=x,1=Wf,2=Uf,3=bf,4=Wi,5=Ui,6=bi,7=Wo,8=Uo,9=bo,10=Wc,11=Uc,12=bc
// d_out (float): hidden_seq [32][2048][256], h_t @16777216, c_t @16785408
//
// This round:
//  (1) rec: counted-vmcnt barrier (asm "s_waitcnt vmcnt(3) lgkmcnt(0); s_barrier")
//      instead of __syncthreads() — stops draining the xg ring prefetch every
//      step (the ~830 cyc/step overhead above the 1024-cyc MFMA-issue floor).
//      h stored per-step so the per-thread VMEM queue is uniform [L,S]x3.
//  (2) proj fused into the rec launch on disjoint blocks: blocks 0..7 run the
//      recurrence on chunk c while blocks 8..8+PB-1 project chunk c+1 into the
//      other xg buffer (Tc=512, double-buffered). Kernel boundary = sync.

typedef int    v4i  __attribute__((ext_vector_type(4)));
typedef float  v4f  __attribute__((ext_vector_type(4)));
typedef __bf16 v8bf __attribute__((ext_vector_type(8)));
typedef __bf16 v4bf __attribute__((ext_vector_type(4)));

#define LOG2E 1.442695040888963f

__device__ __forceinline__ float fast_sigmoid(float x) {
    return __builtin_amdgcn_rcpf(1.f + __builtin_amdgcn_exp2f(-LOG2E * x));
}
__device__ __forceinline__ float fast_tanh(float x) {
    return 1.f - 2.f * __builtin_amdgcn_rcpf(__builtin_amdgcn_exp2f(2.f * LOG2E * x) + 1.f);
}

__device__ __forceinline__ void async_copy16(const void* g, void* l) {
    __builtin_amdgcn_global_load_lds(
        (const __attribute__((address_space(1))) unsigned int*)g,
        (__attribute__((address_space(3))) unsigned int*)l, 16, 0, 0);
}

// ---------------- K1: prep WT (bf16) and qUT (int8) + scales ----------------
__global__ void prep_kernel(
    const float* __restrict__ Wf, const float* __restrict__ Wi,
    const float* __restrict__ Wc, const float* __restrict__ Wo,
    const float* __restrict__ Uf, const float* __restrict__ Ui,
    const float* __restrict__ Uc, const float* __restrict__ Uo,
    __bf16* __restrict__ WT, signed char* __restrict__ qUT,
    float* __restrict__ scales)
{
    int n = blockIdx.x;
    int lane = threadIdx.x;  // 0..63
    if (n < 1024) {
        const float* src = (n < 256) ? Wf : (n < 512) ? Wi : (n < 768) ? Wc : Wo;
        int c = n & 255;
        #pragma unroll
        for (int q = 0; q < 4; ++q) {
            int k = q * 64 + lane;
            WT[n * 256 + k] = (__bf16)src[k * 256 + c];
        }
    } else {
        int nn = n - 1024;
        const float* src = (nn < 256) ? Uf : (nn < 512) ? Ui : (nn < 768) ? Uc : Uo;
        int c = nn & 255;
        float v[4];
        float m = 0.f;
        #pragma unroll
        for (int q = 0; q < 4; ++q) {
            v[q] = src[(q * 64 + lane) * 256 + c];
            m = fmaxf(m, fabsf(v[q]));
        }
        #pragma unroll
        for (int s = 1; s < 64; s <<= 1) m = fmaxf(m, __shfl_xor(m, s));
        float inv = (m > 1e-20f) ? (127.f / m) : 0.f;
        #pragma unroll
        for (int q = 0; q < 4; ++q) {
            int qq = (int)__builtin_rintf(v[q] * inv);
            qUT[nn * 256 + q * 64 + lane] = (signed char)qq;
        }
        if (lane == 0) scales[nn] = m / 16129.f;  // m/(127*127)
    }
}

// ---------------- K2: fused {rec chunk c | proj chunk c+1} ------------------
#define SLOT 8320    // 4 batch-rows, padded stride 2080 (2048 B data each)
#define QHB  1152    // one qh buffer: 4 batches x 288
#define NREC 8

__global__ __launch_bounds__(1024) void fused_kernel(
    // rec args (blocks 0..nrec-1)
    const __bf16* __restrict__ xgR,      // chunk c: [Tc*32][1024] gate-interleaved
    const signed char* __restrict__ qUT, // [1024][256]
    const float* __restrict__ scales,    // [1024]
    float* __restrict__ out,
    int t0, int Tc,
    signed char* __restrict__ qcarry,    // [32][256]
    float* __restrict__ ccarry,          // [32][256]
    int nrec,
    // proj args (blocks nrec..): xg(chunk c+1) = x @ [W] + b
    const float* __restrict__ x, const __bf16* __restrict__ WT,
    const float* __restrict__ bf_, const float* __restrict__ bi_,
    const float* __restrict__ bc_, const float* __restrict__ bo_,
    __bf16* __restrict__ xgP, int t0p)
{
    // overlay: proj uses xs[128][264] bf16 = 67584 B; rec uses 33280+2304 B
    __shared__ __align__(16) char smem[67584];

    const int tid = threadIdx.x;
    const int lane = tid & 63, wid = tid >> 6;
    const int quad = lane >> 4, l16 = lane & 15;

    if ((int)blockIdx.x >= nrec) {
        // ======================= proj path (1024 thr) =======================
        int pb = (int)blockIdx.x - nrec;           // covers 128 rows
        __bf16 (*xs)[264] = (__bf16(*)[264])smem;
        {
            int row = tid >> 3, seg = (tid & 7) * 32;
            int gr = t0p * 32 + pb * 128 + row;    // xg row = t*32 + b
            int bb = gr & 31, tt = gr >> 5;
            const float* xrow = x + ((long)(bb * 2048 + tt)) * 256 + seg;
            #pragma unroll
            for (int q = 0; q < 8; ++q) {
                v4f v = *(const v4f*)(xrow + q * 4);
                v4bf o;
                #pragma unroll
                for (int jj = 0; jj < 4; ++jj) o[jj] = (__bf16)v[jj];
                *(v4bf*)(&xs[row][seg + q * 4]) = o;
            }
        }
        __syncthreads();

        const int wr = (wid & 7) * 16;   // 16-row group
        const int ch = wid >> 3;         // col half (512 cols)

        v8bf af[8];
        #pragma unroll
        for (int kt = 0; kt < 8; ++kt)
            af[kt] = *(const v8bf*)(&xs[wr + l16][kt * 32 + quad * 8]);

        #pragma unroll
        for (int p = 0; p < 4; ++p) {
            v4f acc[8] = {};
            #pragma unroll
            for (int kt = 0; kt < 8; ++kt) {
                int k = kt * 32 + quad * 8;
                #pragma unroll
                for (int nt = 0; nt < 8; ++nt) {
                    int n = ch * 512 + p * 128 + nt * 16 + l16;
                    v8bf bw = *(const v8bf*)(WT + n * 256 + k);
                    acc[nt] = __builtin_amdgcn_mfma_f32_16x16x32_bf16(af[kt], bw, acc[nt], 0, 0, 0);
                }
            }
            #pragma unroll
            for (int nt = 0; nt < 8; ++nt) {
                int n = ch * 512 + p * 128 + nt * 16 + l16;
                const float* bsrc = (n < 256) ? bf_ : (n < 512) ? bi_ : (n < 768) ? bc_ : bo_;
                float bias = bsrc[n & 255];
                int colp = (n & 255) * 4 + (n >> 8);   // gate-interleaved
                #pragma unroll
                for (int rg = 0; rg < 4; ++rg) {
                    int lrow = pb * 128 + wr + quad * 4 + rg;
                    xgP[(long)lrow * 1024 + colp] = (__bf16)(acc[nt][rg] + bias);
                }
            }
        }
        return;
    }

    // ========================== rec path ==========================
    char* ring = smem;                                  // 4*SLOT = 33280 B
    signed char* qh = (signed char*)(smem + 4 * SLOT);  // 2*QHB  =  2304 B

    const int b0 = (int)blockIdx.x * 4;
    const int j = wid * 16 + l16;                // hidden index 0..255

    // persistent B-frags: all 4 gates for hidden col j
    v4i bfr[4][4];
    float scl[4];
    #pragma unroll
    for (int g = 0; g < 4; ++g) {
        int n = g * 256 + j;
        scl[g] = scales[n];
        #pragma unroll
        for (int kt = 0; kt < 4; ++kt)
            bfr[g][kt] = *(const v4i*)(qUT + n * 256 + kt * 64 + quad * 16);
    }

    // zero both qh buffers
    if (tid < (2 * QHB) / 4) ((int*)qh)[tid] = 0;
    __syncthreads();

    float c = 0.f;
    if (t0 != 0) {
        qh[quad * 288 + j] = qcarry[(b0 + quad) * 256 + j];
        c = ccarry[(b0 + quad) * 256 + j];
    }

    // preload ring slots 0..2 (waves 0..7 only: 512 lanes x 16 B = 8 KB/slot)
    const char* xgb = (const char*)xgR;
    const int wrow = wid >> 1, whalf = wid & 1;
    if (tid < 512) {
        #pragma unroll
        for (int s = 0; s < 3; ++s) {
            if (s < Tc) {
                long src = ((long)(s * 32 + b0 + wrow)) * 2048 + whalf * 1024 + (long)lane * 16;
                char* dst = ring + s * SLOT + wrow * 2080 + whalf * 1024;
                async_copy16(xgb + src, dst);
            }
        }
    }

    float* orow = out + ((long)(b0 + quad)) * 2048 * 256 + j;

    for (int tl4 = 0; tl4 < Tc; tl4 += 4) {
        #pragma unroll
        for (int u = 0; u < 4; ++u) {
            const int tl = tl4 + u;
            const int t = t0 + tl;

            // Counted-vmcnt barrier. Per producer thread the queue at this
            // point is [L(t) issued@t-3, S(t-3), L(t+1), S(t-2), L(t+2), S(t-1)]
            // -> vmcnt(3) retires L(t) (+ S(t-3), L(t+1), both long done) while
            // keeping 2 prefetches in flight ACROSS the barrier. Also covers
            // the tail (shorter queues: vmcnt(3) still retires the needed L).
            // lgkmcnt(0): qh double-buffer + ring reads drained pre-barrier.
            // s_barrier fused into the asm: the s_barrier intrinsic is IntrNoMem
            // so memory ops could otherwise be scheduled across it.
            if (u == 0) {
                if (tl4 == 0) {
                    asm volatile("s_waitcnt vmcnt(0) lgkmcnt(0)\n\ts_barrier" ::: "memory");
                } else {
                    asm volatile("s_waitcnt vmcnt(3) lgkmcnt(0)\n\ts_barrier" ::: "memory");
                }
            } else {
                asm volatile("s_waitcnt vmcnt(3) lgkmcnt(0)\n\ts_barrier" ::: "memory");
            }

            // prefetch xg for step tl+3 into slot (u+3)&3
            if (tid < 512 && tl + 3 < Tc) {
                long src = ((long)((tl + 3) * 32 + b0 + wrow)) * 2048 + whalf * 1024 + (long)lane * 16;
                char* dst = ring + ((u + 3) & 3) * SLOT + wrow * 2080 + whalf * 1024;
                async_copy16(xgb + src, dst);
            }

            const signed char* qA = qh + (u & 1) * QHB;
            signed char* qB = qh + ((u + 1) & 1) * QHB;
            const char* xb = ring + (u & 3) * SLOT + quad * 2080;

            // A-frags: every lane reads (rows outside {0,4,8,12} give garbage
            // D-rows we never read — no masking needed)
            v4i a[4];
            #pragma unroll
            for (int kt = 0; kt < 4; ++kt)
                a[kt] = *(const v4i*)(qA + (l16 >> 2) * 288 + kt * 64 + quad * 16);

            // 4 gate pre-activations for (batch=quad, hidden=j): one b64 read
            v4bf xp = *(const v4bf*)(xb + j * 8);

            v4i acc[4];
            #pragma unroll
            for (int g = 0; g < 4; ++g) acc[g] = (v4i){0, 0, 0, 0};
            #pragma unroll
            for (int kt = 0; kt < 4; ++kt) {
                #pragma unroll
                for (int g = 0; g < 4; ++g)
                    acc[g] = __builtin_amdgcn_mfma_i32_16x16x64_i8(a[kt], bfr[g][kt], acc[g], 0, 0, 0);
            }

            // pointwise: one h per lane (batch=quad, hidden=j)
            float zf = (float)xp[0] + scl[0] * (float)acc[0][0];
            float zi = (float)xp[1] + scl[1] * (float)acc[1][0];
            float zg = (float)xp[2] + scl[2] * (float)acc[2][0];
            float zo = (float)xp[3] + scl[3] * (float)acc[3][0];
            float f  = fast_sigmoid(zf);
            float i_ = fast_sigmoid(zi);
            float g_ = fast_tanh(zg);
            float o_ = fast_sigmoid(zo);
            c = f * c + i_ * g_;
            float h = o_ * fast_tanh(c);

            int q = (int)__builtin_rintf(h * 127.f);
            qB[quad * 288 + j] = (signed char)q;
            orow[(long)t * 256] = h;   // per-step store (uniform vmcnt queue)
            if (t == 2047) {
                out[16777216 + (b0 + quad) * 256 + j] = h;
                out[16785408 + (b0 + quad) * 256 + j] = c;
            }
            if (tl == Tc - 1) {
                qcarry[(b0 + quad) * 256 + j] = (signed char)q;
                ccarry[(b0 + quad) * 256 + j] = c;
            }
        }
    }
}

extern "C" void kernel_launch(void* const* d_in, const int* in_sizes, int n_in,
                              void* d_out, int out_size, void* d_ws, size_t ws_size,
                              hipStream_t stream) {
    const float* x   = (const float*)d_in[0];
    const float* Wf  = (const float*)d_in[1];
    const float* Uf  = (const float*)d_in[2];
    const float* bf_ = (const float*)d_in[3];
    const float* Wi  = (const float*)d_in[4];
    const float* Ui  = (const float*)d_in[5];
    const float* bi_ = (const float*)d_in[6];
    const float* Wo  = (const float*)d_in[7];
    const float* Uo  = (const float*)d_in[8];
    const float* bo_ = (const float*)d_in[9];
    const float* Wc  = (const float*)d_in[10];
    const float* Uc  = (const float*)d_in[11];
    const float* bc_ = (const float*)d_in[12];

    char* ws = (char*)d_ws;
    __bf16*      WT     = (__bf16*)ws;                    // 524288 B
    signed char* qUT    = (signed char*)(ws + 524288);    // 262144 B
    float*       scales = (float*)(ws + 786432);          //   4096 B
    signed char* qcarry = (signed char*)(ws + 790528);    //   8192 B
    float*       ccarry = (float*)(ws + 798720);          //  32768 B

    int Tc = 512;   // chunk of timesteps; 2 xg buffers double-buffered
    while (Tc > 8 && 831488ull + 2ull * (unsigned long long)Tc * 65536ull > (unsigned long long)ws_size)
        Tc >>= 1;
    __bf16* xg0 = (__bf16*)(ws + 831488);
    __bf16* xg1 = (__bf16*)(ws + 831488 + (size_t)Tc * 65536);
    int PB = Tc / 4;   // proj blocks per chunk (128 xg-rows each)

    prep_kernel<<<dim3(2048), dim3(64), 0, stream>>>(
        Wf, Wi, Wc, Wo, Uf, Ui, Uc, Uo, WT, qUT, scales);

    // chunk 0 projection (proj-only launch)
    fused_kernel<<<dim3(PB), dim3(1024), 0, stream>>>(
        xg0, qUT, scales, (float*)d_out, 0, Tc, qcarry, ccarry, 0,
        x, WT, bf_, bi_, bc_, bo_, xg0, 0);

    for (int t0 = 0; t0 < 2048; t0 += Tc) {
        int cidx = (t0 / Tc) & 1;
        __bf16* cur = cidx ? xg1 : xg0;
        __bf16* nxt = cidx ? xg0 : xg1;
        int hn = (t0 + Tc) < 2048;
        dim3 grid(hn ? (NREC + PB) : NREC);
        fused_kernel<<<grid, dim3(1024), 0, stream>>>(
            cur, qUT, scales, (float*)d_out, t0, Tc, qcarry, ccarry, NREC,
            x, WT, bf_, bi_, bc_, bo_, nxt, t0 + Tc);
    }
}

// Round 4
// 1757.551 us; speedup vs baseline: 1.1409x; 1.0165x over previous
//
#include <hip/hip_runtime.h>

// LSTM: B=32, S=2048, I=H=256. All global tensors float32.
// d_in: 0=x,1=Wf,2=Uf,3=bf,4=Wi,5=Ui,6=bi,7=Wo,8=Uo,9=bo,10=Wc,11=Uc,12=bc
// d_out (float): hidden_seq [32][2048][256], h_t @16777216, c_t @16785408
//
// R2 changes (theory: 1823 cyc/step = 1306 MFMA floor + ~500 LDS/pointwise):
//  (1) xg ring ELIMINATED: each lane needs only 8 B of xg per step (its 4 gate
//      pre-activations). Load global->VGPR with an 8-step register pipeline
//      (static indices via unroll-8; compiler inserts counted vmcnt waits).
//      Removes: ring global_load_lds LDS-write traffic, xp ds_read_b64, the
//      tid<512 prefetch divergence. Barrier is now lgkmcnt(0)-only.
//  (2) qh write: DPP quad-perm pack (4 bytes -> 1 dword in VALU) + one
//      conflict-free ds_write_b32 per 4 lanes, replacing the 4-way same-dword
//      byte-scatter.
//  (3) chunk-0 projection uses a 64-row/256-thread variant (256 blocks = all
//      CUs) instead of 128 blocks.
// (R4 = identical resubmit: R2/R3 benches died on GPUAcquisitionTimeout.)

typedef int    v4i  __attribute__((ext_vector_type(4)));
typedef float  v4f  __attribute__((ext_vector_type(4)));
typedef __bf16 v8bf __attribute__((ext_vector_type(8)));
typedef __bf16 v4bf __attribute__((ext_vector_type(4)));

#define LOG2E 1.442695040888963f

__device__ __forceinline__ float fast_sigmoid(float x) {
    return __builtin_amdgcn_rcpf(1.f + __builtin_amdgcn_exp2f(-LOG2E * x));
}
__device__ __forceinline__ float fast_tanh(float x) {
    return 1.f - 2.f * __builtin_amdgcn_rcpf(__builtin_amdgcn_exp2f(2.f * LOG2E * x) + 1.f);
}

// ---------------- K1: prep WT (bf16) and qUT (int8) + scales ----------------
__global__ void prep_kernel(
    const float* __restrict__ Wf, const float* __restrict__ Wi,
    const float* __restrict__ Wc, const float* __restrict__ Wo,
    const float* __restrict__ Uf, const float* __restrict__ Ui,
    const float* __restrict__ Uc, const float* __restrict__ Uo,
    __bf16* __restrict__ WT, signed char* __restrict__ qUT,
    float* __restrict__ scales)
{
    int n = blockIdx.x;
    int lane = threadIdx.x;  // 0..63
    if (n < 1024) {
        const float* src = (n < 256) ? Wf : (n < 512) ? Wi : (n < 768) ? Wc : Wo;
        int c = n & 255;
        #pragma unroll
        for (int q = 0; q < 4; ++q) {
            int k = q * 64 + lane;
            WT[n * 256 + k] = (__bf16)src[k * 256 + c];
        }
    } else {
        int nn = n - 1024;
        const float* src = (nn < 256) ? Uf : (nn < 512) ? Ui : (nn < 768) ? Uc : Uo;
        int c = nn & 255;
        float v[4];
        float m = 0.f;
        #pragma unroll
        for (int q = 0; q < 4; ++q) {
            v[q] = src[(q * 64 + lane) * 256 + c];
            m = fmaxf(m, fabsf(v[q]));
        }
        #pragma unroll
        for (int s = 1; s < 64; s <<= 1) m = fmaxf(m, __shfl_xor(m, s));
        float inv = (m > 1e-20f) ? (127.f / m) : 0.f;
        #pragma unroll
        for (int q = 0; q < 4; ++q) {
            int qq = (int)__builtin_rintf(v[q] * inv);
            qUT[nn * 256 + q * 64 + lane] = (signed char)qq;
        }
        if (lane == 0) scales[nn] = m / 16129.f;  // m/(127*127)
    }
}

// ------------- K2a: standalone proj, 64 rows/block, 256 thr (chunk 0) -------
__global__ __launch_bounds__(256) void proj64_kernel(
    const float* __restrict__ x, const __bf16* __restrict__ WT,
    const float* __restrict__ bf_, const float* __restrict__ bi_,
    const float* __restrict__ bc_, const float* __restrict__ bo_,
    __bf16* __restrict__ xg, int t0)
{
    __shared__ __align__(16) __bf16 xs[64][264];   // 264 = 256 + 8 pad

    int tid = threadIdx.x;
    int lane = tid & 63, wid = tid >> 6;
    int quad = lane >> 4, l16 = lane & 15;
    int by = blockIdx.x;

    {
        int row = tid >> 2, seg = (tid & 3) * 64;
        int r = t0 * 32 + by * 64 + row;
        int bb = r & 31, tt = r >> 5;
        const float* xrow = x + ((long)(bb * 2048 + tt)) * 256 + seg;
        #pragma unroll
        for (int q = 0; q < 16; ++q) {
            v4f v = *(const v4f*)(xrow + q * 4);
            v4bf o;
            #pragma unroll
            for (int jj = 0; jj < 4; ++jj) o[jj] = (__bf16)v[jj];
            *(v4bf*)(&xs[row][seg + q * 4]) = o;
        }
    }
    __syncthreads();

    v8bf af[8];
    #pragma unroll
    for (int kt = 0; kt < 8; ++kt)
        af[kt] = *(const v8bf*)(&xs[wid * 16 + l16][kt * 32 + quad * 8]);

    #pragma unroll
    for (int p = 0; p < 8; ++p) {
        v4f acc[8] = {};
        #pragma unroll
        for (int kt = 0; kt < 8; ++kt) {
            int k = kt * 32 + quad * 8;
            #pragma unroll
            for (int nt = 0; nt < 8; ++nt) {
                int n = p * 128 + nt * 16 + l16;
                v8bf bw = *(const v8bf*)(WT + n * 256 + k);
                acc[nt] = __builtin_amdgcn_mfma_f32_16x16x32_bf16(af[kt], bw, acc[nt], 0, 0, 0);
            }
        }
        #pragma unroll
        for (int nt = 0; nt < 8; ++nt) {
            int n = p * 128 + nt * 16 + l16;
            const float* bsrc = (n < 256) ? bf_ : (n < 512) ? bi_ : (n < 768) ? bc_ : bo_;
            float bias = bsrc[n & 255];
            int colp = (n & 255) * 4 + (n >> 8);   // gate-interleaved
            #pragma unroll
            for (int rg = 0; rg < 4; ++rg) {
                int lrow = by * 64 + wid * 16 + quad * 4 + rg;
                xg[(long)lrow * 1024 + colp] = (__bf16)(acc[nt][rg] + bias);
            }
        }
    }
}

// ---------------- K2b: fused {rec chunk c | proj chunk c+1} -----------------
#define QHB  1152    // one qh buffer: 4 batches x 288
#define NREC 8

__global__ __launch_bounds__(1024) void fused_kernel(
    // rec args (blocks 0..nrec-1)
    const __bf16* __restrict__ xgR,      // chunk c: [Tc*32][1024] gate-interleaved
    const signed char* __restrict__ qUT, // [1024][256]
    const float* __restrict__ scales,    // [1024]
    float* __restrict__ out,
    int t0, int Tc,
    signed char* __restrict__ qcarry,    // [32][256]
    float* __restrict__ ccarry,          // [32][256]
    int nrec,
    // proj args (blocks nrec..): xg(chunk c+1) = x @ [W] + b
    const float* __restrict__ x, const __bf16* __restrict__ WT,
    const float* __restrict__ bf_, const float* __restrict__ bi_,
    const float* __restrict__ bc_, const float* __restrict__ bo_,
    __bf16* __restrict__ xgP, int t0p)
{
    // overlay: proj uses xs[128][264] bf16 = 67584 B; rec uses 2*QHB = 2304 B
    __shared__ __align__(16) char smem[67584];

    const int tid = threadIdx.x;
    const int lane = tid & 63, wid = tid >> 6;
    const int quad = lane >> 4, l16 = lane & 15;

    if ((int)blockIdx.x >= nrec) {
        // ======================= proj path (1024 thr) =======================
        int pb = (int)blockIdx.x - nrec;           // covers 128 rows
        __bf16 (*xs)[264] = (__bf16(*)[264])smem;
        {
            int row = tid >> 3, seg = (tid & 7) * 32;
            int gr = t0p * 32 + pb * 128 + row;    // xg row = t*32 + b
            int bb = gr & 31, tt = gr >> 5;
            const float* xrow = x + ((long)(bb * 2048 + tt)) * 256 + seg;
            #pragma unroll
            for (int q = 0; q < 8; ++q) {
                v4f v = *(const v4f*)(xrow + q * 4);
                v4bf o;
                #pragma unroll
                for (int jj = 0; jj < 4; ++jj) o[jj] = (__bf16)v[jj];
                *(v4bf*)(&xs[row][seg + q * 4]) = o;
            }
        }
        __syncthreads();

        const int wr = (wid & 7) * 16;   // 16-row group
        const int ch = wid >> 3;         // col half (512 cols)

        v8bf af[8];
        #pragma unroll
        for (int kt = 0; kt < 8; ++kt)
            af[kt] = *(const v8bf*)(&xs[wr + l16][kt * 32 + quad * 8]);

        #pragma unroll
        for (int p = 0; p < 4; ++p) {
            v4f acc[8] = {};
            #pragma unroll
            for (int kt = 0; kt < 8; ++kt) {
                int k = kt * 32 + quad * 8;
                #pragma unroll
                for (int nt = 0; nt < 8; ++nt) {
                    int n = ch * 512 + p * 128 + nt * 16 + l16;
                    v8bf bw = *(const v8bf*)(WT + n * 256 + k);
                    acc[nt] = __builtin_amdgcn_mfma_f32_16x16x32_bf16(af[kt], bw, acc[nt], 0, 0, 0);
                }
            }
            #pragma unroll
            for (int nt = 0; nt < 8; ++nt) {
                int n = ch * 512 + p * 128 + nt * 16 + l16;
                const float* bsrc = (n < 256) ? bf_ : (n < 512) ? bi_ : (n < 768) ? bc_ : bo_;
                float bias = bsrc[n & 255];
                int colp = (n & 255) * 4 + (n >> 8);   // gate-interleaved
                #pragma unroll
                for (int rg = 0; rg < 4; ++rg) {
                    int lrow = pb * 128 + wr + quad * 4 + rg;
                    xgP[(long)lrow * 1024 + colp] = (__bf16)(acc[nt][rg] + bias);
                }
            }
        }
        return;
    }

    // ========================== rec path ==========================
    signed char* qh = (signed char*)smem;            // 2*QHB = 2304 B

    const int b0 = (int)blockIdx.x * 4;
    const int j = wid * 16 + l16;                    // hidden index 0..255

    // persistent B-frags: all 4 gates for hidden col j
    v4i bfr[4][4];
    float scl[4];
    #pragma unroll
    for (int g = 0; g < 4; ++g) {
        int n = g * 256 + j;
        scl[g] = scales[n];
        #pragma unroll
        for (int kt = 0; kt < 4; ++kt)
            bfr[g][kt] = *(const v4i*)(qUT + n * 256 + kt * 64 + quad * 16);
    }

    // zero both qh buffers
    if (tid < (2 * QHB) / 4) ((int*)qh)[tid] = 0;
    __syncthreads();

    float c = 0.f;
    if (t0 != 0) {
        qh[quad * 288 + j] = qcarry[(b0 + quad) * 256 + j];
        c = ccarry[(b0 + quad) * 256 + j];
    }
    // (qh carry writes become visible via the first loop barrier's lgkmcnt(0))

    // xg register pipeline: this lane's 8 B per step, prefetched 8 steps deep.
    const char* xbase = (const char*)xgR + (long)(b0 + quad) * 2048 + (long)j * 8;
    v4bf xp_cur[8];
    #pragma unroll
    for (int u = 0; u < 8; ++u)
        xp_cur[u] = *(const v4bf*)(xbase + (long)u * 65536);

    float* orow = out + ((long)(b0 + quad)) * 2048 * 256 + j;

    for (int tl8 = 0; tl8 < Tc; tl8 += 8) {
        #pragma unroll
        for (int u = 0; u < 8; ++u) {
            const int tl = tl8 + u;
            const int t = t0 + tl;

            // qh(t-1) writes visible; no vmcnt wait here (xg loads are
            // per-lane register loads with compiler-counted waits).
            asm volatile("s_waitcnt lgkmcnt(0)\n\ts_barrier" ::: "memory");

            const signed char* qA = qh + (u & 1) * QHB;
            signed char* qB = qh + ((u + 1) & 1) * QHB;

            // A-frags (identical across waves; rows outside {0,4,8,12} of D
            // are garbage-by-design and never read)
            v4i a[4];
            #pragma unroll
            for (int kt = 0; kt < 4; ++kt)
                a[kt] = *(const v4i*)(qA + (l16 >> 2) * 288 + kt * 64 + quad * 16);

            // consume this step's xg, refill slot with step tl+8 (clamped)
            v4bf xp = xp_cur[u];
            {
                int tls = tl + 8; if (tls >= Tc) tls = Tc - 1;
                xp_cur[u] = *(const v4bf*)(xbase + (long)tls * 65536);
            }

            v4i acc[4];
            #pragma unroll
            for (int g = 0; g < 4; ++g) acc[g] = (v4i){0, 0, 0, 0};
            #pragma unroll
            for (int kt = 0; kt < 4; ++kt) {
                #pragma unroll
                for (int g = 0; g < 4; ++g)
                    acc[g] = __builtin_amdgcn_mfma_i32_16x16x64_i8(a[kt], bfr[g][kt], acc[g], 0, 0, 0);
            }

            // pointwise: one h per lane (batch=quad, hidden=j)
            float zf = (float)xp[0] + scl[0] * (float)acc[0][0];
            float zi = (float)xp[1] + scl[1] * (float)acc[1][0];
            float zg = (float)xp[2] + scl[2] * (float)acc[2][0];
            float zo = (float)xp[3] + scl[3] * (float)acc[3][0];
            float f  = fast_sigmoid(zf);
            float i_ = fast_sigmoid(zi);
            float g_ = fast_tanh(zg);
            float o_ = fast_sigmoid(zo);
            c = f * c + i_ * g_;
            float h = o_ * fast_tanh(c);

            int q = (int)__builtin_rintf(h * 127.f);

            // DPP pack: 4 neighbor lanes' q-bytes -> 1 dword, one write per 4
            // lanes, conflict-free banks (replaces 4-way same-dword scatter).
            int bq = q & 255;
            int nb = __builtin_amdgcn_update_dpp(0, bq, 0xB1, 0xF, 0xF, true);  // quad_perm [1,0,3,2]
            int c1 = bq | (nb << 8);
            int t2 = __builtin_amdgcn_update_dpp(0, c1, 0x4E, 0xF, 0xF, true);  // quad_perm [2,3,0,1]
            int dw = c1 | (t2 << 16);
            if ((lane & 3) == 0)
                *(int*)(qB + quad * 288 + (j & ~3)) = dw;

            orow[(long)t * 256] = h;
            if (t == 2047) {
                out[16777216 + (b0 + quad) * 256 + j] = h;
                out[16785408 + (b0 + quad) * 256 + j] = c;
            }
            if (tl == Tc - 1) {
                qcarry[(b0 + quad) * 256 + j] = (signed char)q;
                ccarry[(b0 + quad) * 256 + j] = c;
            }
        }
    }
}

extern "C" void kernel_launch(void* const* d_in, const int* in_sizes, int n_in,
                              void* d_out, int out_size, void* d_ws, size_t ws_size,
                              hipStream_t stream) {
    const float* x   = (const float*)d_in[0];
    const float* Wf  = (const float*)d_in[1];
    const float* Uf  = (const float*)d_in[2];
    const float* bf_ = (const float*)d_in[3];
    const float* Wi  = (const float*)d_in[4];
    const float* Ui  = (const float*)d_in[5];
    const float* bi_ = (const float*)d_in[6];
    const float* Wo  = (const float*)d_in[7];
    const float* Uo  = (const float*)d_in[8];
    const float* bo_ = (const float*)d_in[9];
    const float* Wc  = (const float*)d_in[10];
    const float* Uc  = (const float*)d_in[11];
    const float* bc_ = (const float*)d_in[12];

    char* ws = (char*)d_ws;
    __bf16*      WT     = (__bf16*)ws;                    // 524288 B
    signed char* qUT    = (signed char*)(ws + 524288);    // 262144 B
    float*       scales = (float*)(ws + 786432);          //   4096 B
    signed char* qcarry = (signed char*)(ws + 790528);    //   8192 B
    float*       ccarry = (float*)(ws + 798720);          //  32768 B

    int Tc = 512;   // chunk of timesteps; 2 xg buffers double-buffered
    while (Tc > 8 && 831488ull + 2ull * (unsigned long long)Tc * 65536ull > (unsigned long long)ws_size)
        Tc >>= 1;
    __bf16* xg0 = (__bf16*)(ws + 831488);
    __bf16* xg1 = (__bf16*)(ws + 831488 + (size_t)Tc * 65536);
    int PB = Tc / 4;   // proj blocks per fused chunk (128 xg-rows each)

    prep_kernel<<<dim3(2048), dim3(64), 0, stream>>>(
        Wf, Wi, Wc, Wo, Uf, Ui, Uc, Uo, WT, qUT, scales);

    // chunk 0 projection: 64-row blocks -> Tc/2 = 256 blocks (all CUs)
    proj64_kernel<<<dim3(Tc / 2), dim3(256), 0, stream>>>(
        x, WT, bf_, bi_, bc_, bo_, xg0, 0);

    for (int t0 = 0; t0 < 2048; t0 += Tc) {
        int cidx = (t0 / Tc) & 1;
        __bf16* cur = cidx ? xg1 : xg0;
        __bf16* nxt = cidx ? xg0 : xg1;
        int hn = (t0 + Tc) < 2048;
        dim3 grid(hn ? (NREC + PB) : NREC);
        fused_kernel<<<grid, dim3(1024), 0, stream>>>(
            cur, qUT, scales, (float*)d_out, t0, Tc, qcarry, ccarry, NREC,
            x, WT, bf_, bi_, bc_, bo_, nxt, t0 + Tc);
    }
}